// Round 1
// baseline (374.360 us; speedup 1.0000x reference)
//
#include <hip/hip_runtime.h>
#include <math.h>

#define D_FEAT 100
#define ROW_STRIDE 300   // 3 * D_FEAT output blocks concatenated

// ---------------------------------------------------------------------------
// Kernel 1: out[n, 0:100] = tanh(features[n, :])
// ---------------------------------------------------------------------------
__global__ void tanh_feats_kernel(const float* __restrict__ features,
                                  float* __restrict__ out, int total) {
    int i = blockIdx.x * blockDim.x + threadIdx.x;
    if (i >= total) return;
    int n = i / D_FEAT;
    int d = i - n * D_FEAT;
    out[(long)n * ROW_STRIDE + d] = tanhf(features[i]);
}

// ---------------------------------------------------------------------------
// Kernel 2: CSR row offsets via binary search (rows are sorted).
// start[n] = lower_bound(rows, n); start[N] = E.
// adj is interleaved (row, col) pairs: rows at adj[2e].
// ---------------------------------------------------------------------------
__global__ void csr_kernel(const int* __restrict__ adj, int E,
                           int* __restrict__ start, int N) {
    int n = blockIdx.x * blockDim.x + threadIdx.x;
    if (n > N) return;
    if (n == N) { start[N] = E; return; }
    int lo = 0, hi = E;
    while (lo < hi) {
        int mid = (lo + hi) >> 1;
        if (adj[2 * mid] < n) lo = mid + 1; else hi = mid;
    }
    start[n] = lo;
}

// ---------------------------------------------------------------------------
// Kernel 3: one wave (64 lanes) per node, online softmax over its edges.
//   prev: base pointer so prev[col*300 + d] is the previous layer feature
//   outp: base pointer so outp[n*300 + d] is this layer's output slot
// Lane l holds feature elements l and l+64 (masked for l+64 >= 100).
// ---------------------------------------------------------------------------
__global__ __launch_bounds__(256) void attn_kernel(
    const float* __restrict__ prev,
    float* __restrict__ outp,
    const int* __restrict__ adj,
    const int* __restrict__ start,
    const float* __restrict__ none_rel,
    int N)
{
    int wave = (int)((blockIdx.x * blockDim.x + threadIdx.x) >> 6);
    int lane = threadIdx.x & 63;
    if (wave >= N) return;
    const int n  = wave;
    const int l2 = lane + 64;
    const bool has2 = (l2 < D_FEAT);

    // --- normalized none_relation, held in registers (2 elems / lane) ---
    float nr0 = none_rel[lane];
    float nr1 = has2 ? none_rel[l2] : 0.f;
    float ss = nr0 * nr0 + nr1 * nr1;
    #pragma unroll
    for (int off = 32; off; off >>= 1) ss += __shfl_xor(ss, off, 64);
    float inv_nr = 1.f / fmaxf(sqrtf(ss), 1e-12f);
    nr0 *= inv_nr; nr1 *= inv_nr;

    const int e0 = start[n], e1 = start[n + 1];

    // --- online softmax state (wave-uniform scalars + per-lane acc) ---
    float m = -INFINITY, denom = 0.f, acc0 = 0.f, acc1 = 0.f;

    for (int e = e0; e < e1; ++e) {
        int col = adj[2 * e + 1];
        const float* p = prev + (long)col * ROW_STRIDE;
        float x0 = p[lane];
        float x1 = has2 ? p[l2] : 0.f;

        float dot = x0 * nr0 + x1 * nr1;
        float sq  = x0 * x0 + x1 * x1;
        #pragma unroll
        for (int off = 32; off; off >>= 1) {
            dot += __shfl_xor(dot, off, 64);
            sq  += __shfl_xor(sq,  off, 64);
        }
        // score = -dot(l2norm(x), nr)
        float s = -dot / fmaxf(sqrtf(sq), 1e-12f);

        // online softmax update (wave-uniform branch: s,m identical on all lanes)
        if (s > m) {
            float c = expf(m - s);   // expf(-inf) = 0 on first edge
            denom *= c; acc0 *= c; acc1 *= c;
            m = s;
        }
        float w = expf(s - m);
        denom += w;
        acc0 += w * x0;
        acc1 += w * x1;
    }

    float r0 = 0.f, r1 = 0.f;
    if (e1 > e0) {
        float id = 1.f / denom;
        r0 = tanhf(acc0 * id);
        r1 = tanhf(acc1 * id);
    }
    float* o = outp + (long)n * ROW_STRIDE;
    o[lane] = r0;
    if (has2) o[l2] = r1;
}

// ---------------------------------------------------------------------------
extern "C" void kernel_launch(void* const* d_in, const int* in_sizes, int n_in,
                              void* d_out, int out_size, void* d_ws, size_t ws_size,
                              hipStream_t stream) {
    const float* features = (const float*)d_in[0];
    // d_in[1] = rel_emb: unused by the reference
    const int*   adj      = (const int*)d_in[2];
    const float* none_rel = (const float*)d_in[3];
    float* out = (float*)d_out;

    const int N = in_sizes[0] / D_FEAT;   // 50000
    const int E = in_sizes[2] / 2;        // 800000
    int* start = (int*)d_ws;              // (N+1) ints of scratch

    // outputs[0] = tanh(features) -> out[:, 0:100]
    {
        int total = N * D_FEAT;
        int blocks = (total + 255) / 256;
        tanh_feats_kernel<<<blocks, 256, 0, stream>>>(features, out, total);
    }
    // CSR offsets (rows sorted)
    {
        int blocks = (N + 1 + 255) / 256;
        csr_kernel<<<blocks, 256, 0, stream>>>(adj, E, start, N);
    }
    // depth 1: read cols [0,100), write cols [100,200)
    // depth 2: read cols [100,200), write cols [200,300)
    {
        int blocks = (N * 64 + 255) / 256;   // one 64-lane wave per node
        attn_kernel<<<blocks, 256, 0, stream>>>(out, out + D_FEAT,
                                                adj, start, none_rel, N);
        attn_kernel<<<blocks, 256, 0, stream>>>(out + D_FEAT, out + 2 * D_FEAT,
                                                adj, start, none_rel, N);
    }
}

// Round 2
// 310.797 us; speedup vs baseline: 1.2045x; 1.2045x over previous
//
#include <hip/hip_runtime.h>
#include <math.h>
#include <float.h>

#define D_FEAT 100
#define ROW_STRIDE 300   // 3 * D_FEAT output blocks concatenated

// ---------------------------------------------------------------------------
// Kernel 1: one wave per node.
//   out[n, 0:100] = tanh(features[n, :])
//   score0[n]     = -dot(l2norm(out[n,0:100]), l2norm(none_rel))
// Lane l holds elements l and l+64 (masked for l+64 >= 100).
// ---------------------------------------------------------------------------
__global__ __launch_bounds__(256) void tanh_score_kernel(
    const float* __restrict__ features,
    float* __restrict__ out,
    float* __restrict__ score0,
    const float* __restrict__ none_rel,
    int N)
{
    int wave = (int)((blockIdx.x * blockDim.x + threadIdx.x) >> 6);
    int lane = threadIdx.x & 63;
    if (wave >= N) return;
    const int n  = wave;
    const int l2 = lane + 64;
    const bool has2 = (l2 < D_FEAT);

    // normalized none_relation (2 elems / lane)
    float nr0 = none_rel[lane];
    float nr1 = has2 ? none_rel[l2] : 0.f;
    float ss = nr0 * nr0 + nr1 * nr1;
    #pragma unroll
    for (int off = 32; off; off >>= 1) ss += __shfl_xor(ss, off, 64);
    float inv_nr = 1.f / fmaxf(sqrtf(ss), 1e-12f);
    nr0 *= inv_nr; nr1 *= inv_nr;

    float x0 = tanhf(features[(long)n * D_FEAT + lane]);
    float x1 = has2 ? tanhf(features[(long)n * D_FEAT + l2]) : 0.f;

    float* o = out + (long)n * ROW_STRIDE;
    o[lane] = x0;
    if (has2) o[l2] = x1;

    float dot = x0 * nr0 + x1 * nr1;
    float sq  = x0 * x0 + x1 * x1;
    #pragma unroll
    for (int off = 32; off; off >>= 1) {
        dot += __shfl_xor(dot, off, 64);
        sq  += __shfl_xor(sq,  off, 64);
    }
    if (lane == 0)
        score0[n] = -dot / fmaxf(sqrtf(sq), 1e-12f);
}

// ---------------------------------------------------------------------------
// Kernel 2: CSR row offsets via binary search (rows are sorted).
// ---------------------------------------------------------------------------
__global__ void csr_kernel(const int* __restrict__ adj, int E,
                           int* __restrict__ start, int N) {
    int n = blockIdx.x * blockDim.x + threadIdx.x;
    if (n > N) return;
    if (n == N) { start[N] = E; return; }
    int lo = 0, hi = E;
    while (lo < hi) {
        int mid = (lo + hi) >> 1;
        if (adj[2 * mid] < n) lo = mid + 1; else hi = mid;
    }
    start[n] = lo;
}

// ---------------------------------------------------------------------------
// Kernel 3: one wave per node.
//  Pass 1 (lanes over edges): softmax max + denom from precomputed node scores.
//  Pass 2 (lanes over features): weighted aggregation, edges serial.
//  Epilogue: tanh, write features; optionally emit this layer's node scores.
// ---------------------------------------------------------------------------
__global__ __launch_bounds__(256) void attn_kernel(
    const float* __restrict__ prev,      // prev-layer features, stride 300
    float* __restrict__ outp,            // this-layer features, stride 300
    const int* __restrict__ adj,
    const int* __restrict__ start,
    const float* __restrict__ score_in,  // per-node scores of prev layer
    float* __restrict__ score_out,       // per-node scores of this layer (or null)
    const float* __restrict__ none_rel,
    int N)
{
    int wave = (int)((blockIdx.x * blockDim.x + threadIdx.x) >> 6);
    int lane = threadIdx.x & 63;
    if (wave >= N) return;
    const int n  = wave;
    const int l2 = lane + 64;
    const bool has2 = (l2 < D_FEAT);

    const int e0 = start[n], e1 = start[n + 1];

    // ---- Pass 1: online (max, denom) per lane over edges, then butterfly ----
    float m_l = -FLT_MAX, d_l = 0.f;
    for (int e = e0 + lane; e < e1; e += 64) {
        int col = adj[2 * e + 1];
        float s = score_in[col];
        if (s > m_l) {
            d_l = d_l * expf(m_l - s) + 1.f;   // expf(-FLT_MAX - s) -> 0 on first hit
            m_l = s;
        } else {
            d_l += expf(s - m_l);
        }
    }
    #pragma unroll
    for (int off = 32; off; off >>= 1) {
        float m2 = __shfl_xor(m_l, off, 64);
        float d2 = __shfl_xor(d_l, off, 64);
        float M  = fmaxf(m_l, m2);
        // both-empty pair: m_l==m2==-FLT_MAX -> exp(0)=1, d stays 0 (no NaN)
        d_l = d_l * expf(m_l - M) + d2 * expf(m2 - M);
        m_l = M;
    }
    const float m = m_l;
    const float inv_d = (e1 > e0) ? 1.f / d_l : 0.f;

    // ---- Pass 2: weighted feature aggregation, edges serial ----
    float acc0 = 0.f, acc1 = 0.f;
    for (int e = e0; e < e1; ++e) {
        int col = adj[2 * e + 1];
        const float* p = prev + (long)col * ROW_STRIDE;
        float w  = expf(score_in[col] - m);
        float x0 = p[lane];
        float x1 = has2 ? p[l2] : 0.f;
        acc0 += w * x0;
        acc1 += w * x1;
    }

    float r0 = tanhf(acc0 * inv_d);
    float r1 = tanhf(acc1 * inv_d);
    float* o = outp + (long)n * ROW_STRIDE;
    o[lane] = r0;
    if (has2) o[l2] = r1;

    // ---- Epilogue: next layer's node score from registers ----
    if (score_out) {
        float nr0 = none_rel[lane];
        float nr1 = has2 ? none_rel[l2] : 0.f;
        float ss = nr0 * nr0 + nr1 * nr1;
        #pragma unroll
        for (int off = 32; off; off >>= 1) ss += __shfl_xor(ss, off, 64);
        float inv_nr = 1.f / fmaxf(sqrtf(ss), 1e-12f);
        nr0 *= inv_nr; nr1 *= inv_nr;

        float dot = r0 * nr0 + r1 * nr1;
        float sq  = r0 * r0 + r1 * r1;
        #pragma unroll
        for (int off = 32; off; off >>= 1) {
            dot += __shfl_xor(dot, off, 64);
            sq  += __shfl_xor(sq,  off, 64);
        }
        if (lane == 0)
            score_out[n] = -dot / fmaxf(sqrtf(sq), 1e-12f);
    }
}

// ---------------------------------------------------------------------------
extern "C" void kernel_launch(void* const* d_in, const int* in_sizes, int n_in,
                              void* d_out, int out_size, void* d_ws, size_t ws_size,
                              hipStream_t stream) {
    const float* features = (const float*)d_in[0];
    // d_in[1] = rel_emb: unused by the reference
    const int*   adj      = (const int*)d_in[2];
    const float* none_rel = (const float*)d_in[3];
    float* out = (float*)d_out;

    const int N = in_sizes[0] / D_FEAT;   // 50000
    const int E = in_sizes[2] / 2;        // 800000

    // workspace layout: start[N+1] | score0[N] | score1[N]
    int*   start  = (int*)d_ws;
    float* score0 = (float*)((char*)d_ws + sizeof(int) * (size_t)(N + 1));
    float* score1 = score0 + N;

    const int node_blocks = (N * 64 + 255) / 256;   // one wave per node

    tanh_score_kernel<<<node_blocks, 256, 0, stream>>>(features, out, score0,
                                                       none_rel, N);
    {
        int blocks = (N + 1 + 255) / 256;
        csr_kernel<<<blocks, 256, 0, stream>>>(adj, E, start, N);
    }
    // depth 1: read cols [0,100), write [100,200), emit score1
    attn_kernel<<<node_blocks, 256, 0, stream>>>(out, out + D_FEAT,
                                                 adj, start, score0, score1,
                                                 none_rel, N);
    // depth 2: read cols [100,200), write [200,300), no score needed
    attn_kernel<<<node_blocks, 256, 0, stream>>>(out + D_FEAT, out + 2 * D_FEAT,
                                                 adj, start, score1, nullptr,
                                                 none_rel, N);
}

// Round 3
// 237.533 us; speedup vs baseline: 1.5760x; 1.3084x over previous
//
#include <hip/hip_runtime.h>
#include <math.h>

#define D_FEAT 100
#define ROW_STRIDE 300   // 3 * D_FEAT output blocks concatenated

// ---------------------------------------------------------------------------
// Kernel 1: one wave per node.
//   out[n, 0:100] = tanh(features[n, :])
//   escore0[n]    = exp(-dot(l2norm(out[n,0:100]), l2norm(none_rel)))
// Score is a dot of unit vectors -> in [-1,1], so exp() without max-shift
// is safe and matches softmax exactly.
// ---------------------------------------------------------------------------
__global__ __launch_bounds__(256) void tanh_score_kernel(
    const float* __restrict__ features,
    float* __restrict__ out,
    float* __restrict__ escore0,
    const float* __restrict__ none_rel,
    int N)
{
    int wave = (int)((blockIdx.x * blockDim.x + threadIdx.x) >> 6);
    int lane = threadIdx.x & 63;
    if (wave >= N) return;
    const int n  = wave;
    const int l2 = lane + 64;
    const bool has2 = (l2 < D_FEAT);

    float nr0 = none_rel[lane];
    float nr1 = has2 ? none_rel[l2] : 0.f;
    float ss = nr0 * nr0 + nr1 * nr1;
    #pragma unroll
    for (int off = 32; off; off >>= 1) ss += __shfl_xor(ss, off, 64);
    float inv_nr = 1.f / fmaxf(sqrtf(ss), 1e-12f);
    nr0 *= inv_nr; nr1 *= inv_nr;

    float x0 = tanhf(features[(long)n * D_FEAT + lane]);
    float x1 = has2 ? tanhf(features[(long)n * D_FEAT + l2]) : 0.f;

    float* o = out + (long)n * ROW_STRIDE;
    o[lane] = x0;
    if (has2) o[l2] = x1;

    float dot = x0 * nr0 + x1 * nr1;
    float sq  = x0 * x0 + x1 * x1;
    #pragma unroll
    for (int off = 32; off; off >>= 1) {
        dot += __shfl_xor(dot, off, 64);
        sq  += __shfl_xor(sq,  off, 64);
    }
    if (lane == 0)
        escore0[n] = expf(-dot / fmaxf(sqrtf(sq), 1e-12f));
}

// ---------------------------------------------------------------------------
// Kernel 2: CSR row offsets via binary search (rows are sorted).
// ---------------------------------------------------------------------------
__global__ void csr_kernel(const int* __restrict__ adj, int E,
                           int* __restrict__ start, int N) {
    int n = blockIdx.x * blockDim.x + threadIdx.x;
    if (n > N) return;
    if (n == N) { start[N] = E; return; }
    int lo = 0, hi = E;
    while (lo < hi) {
        int mid = (lo + hi) >> 1;
        if (adj[2 * mid] < n) lo = mid + 1; else hi = mid;
    }
    start[n] = lo;
}

// ---------------------------------------------------------------------------
// Kernel 3: edge weights: edge_w[e] = escore[col[e]]  (E-parallel gather)
// ---------------------------------------------------------------------------
__global__ void edgew_kernel(const int* __restrict__ adj,
                             const float* __restrict__ escore,
                             float* __restrict__ edge_w, int E) {
    int e = blockIdx.x * blockDim.x + threadIdx.x;
    if (e < E) edge_w[e] = escore[adj[2 * e + 1]];
}

// ---------------------------------------------------------------------------
// Kernel 4: one wave per node.
//  Pass 1: denom = sum(edge_w[e0..e1)) — coalesced lanes-over-edges.
//  Pass 2: weighted feature aggregation, 4-way unrolled gather.
//  Epilogue: tanh, write features; optionally emit exp-scores for next depth.
// ---------------------------------------------------------------------------
__global__ __launch_bounds__(256) void attn_kernel(
    const float* __restrict__ prev,      // prev-layer features, stride 300
    float* __restrict__ outp,            // this-layer features, stride 300
    const int* __restrict__ adj,
    const int* __restrict__ start,
    const float* __restrict__ edge_w,    // per-edge softmax numerators
    float* __restrict__ escore_out,      // exp-scores of this layer (or null)
    const float* __restrict__ none_rel,
    int N)
{
    int wave = (int)((blockIdx.x * blockDim.x + threadIdx.x) >> 6);
    int lane = threadIdx.x & 63;
    if (wave >= N) return;
    const int n  = wave;
    const int l2 = lane + 64;
    const bool has2 = (l2 < D_FEAT);

    const int e0 = start[n], e1 = start[n + 1];

    // ---- Pass 1: denominator (coalesced) ----
    float d_l = 0.f;
    for (int e = e0 + lane; e < e1; e += 64) d_l += edge_w[e];
    #pragma unroll
    for (int off = 32; off; off >>= 1) d_l += __shfl_xor(d_l, off, 64);
    const float inv_d = (e1 > e0) ? 1.f / d_l : 0.f;

    // ---- Pass 2: weighted feature aggregation, 4 gathers in flight ----
    const int2* adj2 = (const int2*)adj;
    float acc0 = 0.f, acc1 = 0.f;
    int e = e0;
    for (; e + 4 <= e1; e += 4) {
        int c0 = adj2[e].y, c1 = adj2[e + 1].y, c2 = adj2[e + 2].y, c3 = adj2[e + 3].y;
        float w0 = edge_w[e],     w1 = edge_w[e + 1];
        float w2 = edge_w[e + 2], w3 = edge_w[e + 3];
        const float* p0 = prev + (long)c0 * ROW_STRIDE;
        const float* p1 = prev + (long)c1 * ROW_STRIDE;
        const float* p2 = prev + (long)c2 * ROW_STRIDE;
        const float* p3 = prev + (long)c3 * ROW_STRIDE;
        float a0 = p0[lane], a1 = p1[lane], a2 = p2[lane], a3 = p3[lane];
        float b0 = 0.f, b1 = 0.f, b2 = 0.f, b3 = 0.f;
        if (has2) { b0 = p0[l2]; b1 = p1[l2]; b2 = p2[l2]; b3 = p3[l2]; }
        acc0 += w0 * a0; acc1 += w0 * b0;
        acc0 += w1 * a1; acc1 += w1 * b1;
        acc0 += w2 * a2; acc1 += w2 * b2;
        acc0 += w3 * a3; acc1 += w3 * b3;
    }
    for (; e < e1; ++e) {
        int c = adj2[e].y;
        float w = edge_w[e];
        const float* p = prev + (long)c * ROW_STRIDE;
        acc0 += w * p[lane];
        if (has2) acc1 += w * p[l2];
    }

    float r0 = tanhf(acc0 * inv_d);
    float r1 = tanhf(acc1 * inv_d);
    float* o = outp + (long)n * ROW_STRIDE;
    o[lane] = r0;
    if (has2) o[l2] = r1;

    // ---- Epilogue: next layer's exp-score from registers ----
    if (escore_out) {
        float nr0 = none_rel[lane];
        float nr1 = has2 ? none_rel[l2] : 0.f;
        float ss = nr0 * nr0 + nr1 * nr1;
        #pragma unroll
        for (int off = 32; off; off >>= 1) ss += __shfl_xor(ss, off, 64);
        float inv_nr = 1.f / fmaxf(sqrtf(ss), 1e-12f);
        nr0 *= inv_nr; nr1 *= inv_nr;

        float dot = r0 * nr0 + r1 * nr1;
        float sq  = r0 * r0 + r1 * r1;
        #pragma unroll
        for (int off = 32; off; off >>= 1) {
            dot += __shfl_xor(dot, off, 64);
            sq  += __shfl_xor(sq,  off, 64);
        }
        if (lane == 0)
            escore_out[n] = expf(-dot / fmaxf(sqrtf(sq), 1e-12f));
    }
}

// ---------------------------------------------------------------------------
extern "C" void kernel_launch(void* const* d_in, const int* in_sizes, int n_in,
                              void* d_out, int out_size, void* d_ws, size_t ws_size,
                              hipStream_t stream) {
    const float* features = (const float*)d_in[0];
    // d_in[1] = rel_emb: unused by the reference
    const int*   adj      = (const int*)d_in[2];
    const float* none_rel = (const float*)d_in[3];
    float* out = (float*)d_out;

    const int N = in_sizes[0] / D_FEAT;   // 50000
    const int E = in_sizes[2] / 2;        // 800000

    // workspace: start[N+1] | escore0[N] | escore1[N] | edge_w[E]
    int*   start   = (int*)d_ws;
    float* escore0 = (float*)((char*)d_ws + sizeof(int) * (size_t)(N + 1));
    float* escore1 = escore0 + N;
    float* edge_w  = escore1 + N;

    const int node_blocks = (N * 64 + 255) / 256;   // one wave per node
    const int edge_blocks = (E + 255) / 256;

    tanh_score_kernel<<<node_blocks, 256, 0, stream>>>(features, out, escore0,
                                                       none_rel, N);
    {
        int blocks = (N + 1 + 255) / 256;
        csr_kernel<<<blocks, 256, 0, stream>>>(adj, E, start, N);
    }
    // depth 1
    edgew_kernel<<<edge_blocks, 256, 0, stream>>>(adj, escore0, edge_w, E);
    attn_kernel<<<node_blocks, 256, 0, stream>>>(out, out + D_FEAT,
                                                 adj, start, edge_w, escore1,
                                                 none_rel, N);
    // depth 2
    edgew_kernel<<<edge_blocks, 256, 0, stream>>>(adj, escore1, edge_w, E);
    attn_kernel<<<node_blocks, 256, 0, stream>>>(out + D_FEAT, out + 2 * D_FEAT,
                                                 adj, start, edge_w, nullptr,
                                                 none_rel, N);
}

// Round 4
// 226.393 us; speedup vs baseline: 1.6536x; 1.0492x over previous
//
#include <hip/hip_runtime.h>
#include <math.h>

#define D_FEAT 100
#define HALF   50          // active lanes: lane l holds elements 2l, 2l+1
#define ROW_STRIDE 300     // 3 * D_FEAT concatenated output blocks

// ---------------------------------------------------------------------------
// bf16x2 pack (RNE) — two tanh-bounded floats into one dword.
// ---------------------------------------------------------------------------
__device__ __forceinline__ unsigned pack_bf16x2(float a, float b) {
    unsigned ua = __float_as_uint(a);
    unsigned ub = __float_as_uint(b);
    ua += 0x7fffu + ((ua >> 16) & 1u);
    ub += 0x7fffu + ((ub >> 16) & 1u);
    return (ua >> 16) | (ub & 0xffff0000u);
}

// gather 2 feature elements for `col` (bf16 packed table or f32 stride-300)
template <bool BF16>
__device__ __forceinline__ void gather2(const void* __restrict__ prev, int col,
                                        int lane, bool act, float& x0, float& x1) {
    x0 = 0.f; x1 = 0.f;
    if (!act) return;
    if (BF16) {
        unsigned u = ((const unsigned*)prev)[(size_t)col * HALF + lane];
        x0 = __uint_as_float(u << 16);
        x1 = __uint_as_float(u & 0xffff0000u);
    } else {
        float2 v = ((const float2*)((const float*)prev + (size_t)col * ROW_STRIDE))[lane];
        x0 = v.x; x1 = v.y;
    }
}

// ---------------------------------------------------------------------------
// Kernel 1: one wave per node.
//   out[n,0:100] = tanh(features[n,:]);  ftab0[n] = bf16(out row) (optional)
//   escore0[n] = exp(-dot(l2norm(row), l2norm(none_rel)))   [score in [-1,1]]
// ---------------------------------------------------------------------------
__global__ __launch_bounds__(256) void tanh_score_kernel(
    const float* __restrict__ features,
    float* __restrict__ out,
    unsigned* __restrict__ ftab0,        // packed bf16x2 table or null
    float* __restrict__ escore0,
    const float* __restrict__ none_rel,
    int N)
{
    int wave = (int)((blockIdx.x * blockDim.x + threadIdx.x) >> 6);
    int lane = threadIdx.x & 63;
    if (wave >= N) return;
    const bool act = (lane < HALF);

    float nr0 = 0.f, nr1 = 0.f;
    if (act) { float2 v = ((const float2*)none_rel)[lane]; nr0 = v.x; nr1 = v.y; }
    float ss = nr0 * nr0 + nr1 * nr1;
    #pragma unroll
    for (int off = 32; off; off >>= 1) ss += __shfl_xor(ss, off, 64);
    float inv_nr = 1.f / fmaxf(sqrtf(ss), 1e-12f);
    nr0 *= inv_nr; nr1 *= inv_nr;

    float x0 = 0.f, x1 = 0.f;
    if (act) {
        float2 f = ((const float2*)(features + (size_t)wave * D_FEAT))[lane];
        x0 = tanhf(f.x); x1 = tanhf(f.y);
        ((float2*)(out + (size_t)wave * ROW_STRIDE))[lane] = make_float2(x0, x1);
        if (ftab0) ftab0[(size_t)wave * HALF + lane] = pack_bf16x2(x0, x1);
    }

    float dot = x0 * nr0 + x1 * nr1;
    float sq  = x0 * x0 + x1 * x1;
    #pragma unroll
    for (int off = 32; off; off >>= 1) {
        dot += __shfl_xor(dot, off, 64);
        sq  += __shfl_xor(sq,  off, 64);
    }
    if (lane == 0)
        escore0[wave] = expf(-dot / fmaxf(sqrtf(sq), 1e-12f));
}

// ---------------------------------------------------------------------------
// Kernel 2: CSR row offsets via binary search (rows are sorted).
// ---------------------------------------------------------------------------
__global__ void csr_kernel(const int* __restrict__ adj, int E,
                           int* __restrict__ start, int N) {
    int n = blockIdx.x * blockDim.x + threadIdx.x;
    if (n > N) return;
    if (n == N) { start[N] = E; return; }
    int lo = 0, hi = E;
    while (lo < hi) {
        int mid = (lo + hi) >> 1;
        if (adj[2 * mid] < n) lo = mid + 1; else hi = mid;
    }
    start[n] = lo;
}

// ---------------------------------------------------------------------------
// Kernel 3: one wave per node, fully fused attention layer.
//  Pass 1 (lanes over edges): gather escore[col]; keep (col,w) in lane regs;
//          butterfly-sum -> denom.  exp() needs no max-shift: score in [-1,1].
//  Pass 2: deg<=64 fast path broadcasts (col,w) via shfl; 1 gather load/edge.
//  Epilogue: tanh -> f32 out (+ bf16 table, + next exp-score).
// ---------------------------------------------------------------------------
template <bool BF16>
__global__ __launch_bounds__(256) void attn_kernel(
    const void* __restrict__ prev,       // BF16 ? packed table : f32 stride-300
    float* __restrict__ outp,            // this layer f32 slice (stride 300)
    unsigned* __restrict__ ftab_out,     // next bf16 table or null
    const int* __restrict__ adj,
    const int* __restrict__ start,
    const float* __restrict__ escore_in,
    float* __restrict__ escore_out,      // or null
    const float* __restrict__ none_rel,
    int N)
{
    int wave = (int)((blockIdx.x * blockDim.x + threadIdx.x) >> 6);
    int lane = threadIdx.x & 63;
    if (wave >= N) return;
    const int n = wave;
    const bool act = (lane < HALF);

    const int e0 = start[n], e1 = start[n + 1];
    const int deg = e1 - e0;

    // ---- Pass 1: per-lane gather of (col, w); denominator reduce ----
    int   col_reg = 0;
    float w_reg = 0.f, d_l = 0.f;
    if (lane < deg) {
        col_reg = adj[2 * (e0 + lane) + 1];
        w_reg = escore_in[col_reg];
        d_l = w_reg;
    }
    for (int e = e0 + lane + 64; e < e1; e += 64)
        d_l += escore_in[adj[2 * e + 1]];
    #pragma unroll
    for (int off = 32; off; off >>= 1) d_l += __shfl_xor(d_l, off, 64);
    const float inv_d = (deg > 0) ? 1.f / d_l : 0.f;

    // ---- Pass 2: weighted aggregation ----
    float acc0 = 0.f, acc1 = 0.f;
    if (deg <= 64) {
        int i = 0;
        for (; i + 4 <= deg; i += 4) {
            int   c0 = __shfl(col_reg, i,     64), c1 = __shfl(col_reg, i + 1, 64);
            int   c2 = __shfl(col_reg, i + 2, 64), c3 = __shfl(col_reg, i + 3, 64);
            float w0 = __shfl(w_reg,   i,     64), w1 = __shfl(w_reg,   i + 1, 64);
            float w2 = __shfl(w_reg,   i + 2, 64), w3 = __shfl(w_reg,   i + 3, 64);
            float a0, b0, a1, b1, a2, b2, a3, b3;
            gather2<BF16>(prev, c0, lane, act, a0, b0);
            gather2<BF16>(prev, c1, lane, act, a1, b1);
            gather2<BF16>(prev, c2, lane, act, a2, b2);
            gather2<BF16>(prev, c3, lane, act, a3, b3);
            acc0 += w0 * a0; acc1 += w0 * b0;
            acc0 += w1 * a1; acc1 += w1 * b1;
            acc0 += w2 * a2; acc1 += w2 * b2;
            acc0 += w3 * a3; acc1 += w3 * b3;
        }
        for (; i < deg; ++i) {
            int   c = __shfl(col_reg, i, 64);
            float w = __shfl(w_reg, i, 64);
            float a, b;
            gather2<BF16>(prev, c, lane, act, a, b);
            acc0 += w * a; acc1 += w * b;
        }
    } else {
        for (int e = e0; e < e1; ++e) {
            int   c = adj[2 * e + 1];
            float w = escore_in[c];
            float a, b;
            gather2<BF16>(prev, c, lane, act, a, b);
            acc0 += w * a; acc1 += w * b;
        }
    }

    float r0 = tanhf(acc0 * inv_d);
    float r1 = tanhf(acc1 * inv_d);
    if (act) {
        ((float2*)(outp + (size_t)n * ROW_STRIDE))[lane] = make_float2(r0, r1);
        if (ftab_out) ftab_out[(size_t)n * HALF + lane] = pack_bf16x2(r0, r1);
    } else { r0 = 0.f; r1 = 0.f; }

    // ---- Epilogue: next layer's exp-score ----
    if (escore_out) {
        float nr0 = 0.f, nr1 = 0.f;
        if (act) { float2 v = ((const float2*)none_rel)[lane]; nr0 = v.x; nr1 = v.y; }
        float ss = nr0 * nr0 + nr1 * nr1;
        #pragma unroll
        for (int off = 32; off; off >>= 1) ss += __shfl_xor(ss, off, 64);
        float inv_nr = 1.f / fmaxf(sqrtf(ss), 1e-12f);
        nr0 *= inv_nr; nr1 *= inv_nr;

        float dot = r0 * nr0 + r1 * nr1;
        float sq  = r0 * r0 + r1 * r1;
        #pragma unroll
        for (int off = 32; off; off >>= 1) {
            dot += __shfl_xor(dot, off, 64);
            sq  += __shfl_xor(sq,  off, 64);
        }
        if (lane == 0)
            escore_out[n] = expf(-dot / fmaxf(sqrtf(sq), 1e-12f));
    }
}

// ---------------------------------------------------------------------------
extern "C" void kernel_launch(void* const* d_in, const int* in_sizes, int n_in,
                              void* d_out, int out_size, void* d_ws, size_t ws_size,
                              hipStream_t stream) {
    const float* features = (const float*)d_in[0];
    // d_in[1] = rel_emb: unused by the reference
    const int*   adj      = (const int*)d_in[2];
    const float* none_rel = (const float*)d_in[3];
    float* out = (float*)d_out;

    const int N = in_sizes[0] / D_FEAT;   // 50000
    const int E = in_sizes[2] / 2;        // 800000

    // ws layout (16B-aligned): start[N+1] | escore0[N] | escore1[N]
    //                          | ftab0[N*50 u32] | ftab1[N*50 u32]
    size_t off = 0;
    auto take = [&](size_t bytes) { size_t o = off; off = (off + bytes + 15) & ~(size_t)15; return o; };
    char* w = (char*)d_ws;
    int*      start   = (int*)     (w + take(sizeof(int)   * (size_t)(N + 1)));
    float*    escore0 = (float*)   (w + take(sizeof(float) * (size_t)N));
    float*    escore1 = (float*)   (w + take(sizeof(float) * (size_t)N));
    size_t ftab_off0 = take(sizeof(unsigned) * (size_t)N * HALF);
    size_t ftab_off1 = take(sizeof(unsigned) * (size_t)N * HALF);
    const bool use_bf16 = (ws_size >= off);
    unsigned* ftab0 = use_bf16 ? (unsigned*)(w + ftab_off0) : nullptr;
    unsigned* ftab1 = use_bf16 ? (unsigned*)(w + ftab_off1) : nullptr;

    const int node_blocks = (N * 64 + 255) / 256;   // one wave per node

    tanh_score_kernel<<<node_blocks, 256, 0, stream>>>(features, out, ftab0,
                                                       escore0, none_rel, N);
    {
        int blocks = (N + 1 + 255) / 256;
        csr_kernel<<<blocks, 256, 0, stream>>>(adj, E, start, N);
    }
    if (use_bf16) {
        attn_kernel<true><<<node_blocks, 256, 0, stream>>>(
            ftab0, out + D_FEAT, ftab1, adj, start, escore0, escore1, none_rel, N);
        attn_kernel<true><<<node_blocks, 256, 0, stream>>>(
            ftab1, out + 2 * D_FEAT, nullptr, adj, start, escore1, nullptr, none_rel, N);
    } else {
        attn_kernel<false><<<node_blocks, 256, 0, stream>>>(
            out, out + D_FEAT, nullptr, adj, start, escore0, escore1, none_rel, N);
        attn_kernel<false><<<node_blocks, 256, 0, stream>>>(
            out + D_FEAT, out + 2 * D_FEAT, nullptr, adj, start, escore1, nullptr, none_rel, N);
    }
}

// Round 5
// 188.139 us; speedup vs baseline: 1.9898x; 1.2033x over previous
//
#include <hip/hip_runtime.h>
#include <math.h>

#define D_FEAT 100
#define QUARTER 25         // active lanes per 32-lane half: lane l holds elems 4l..4l+3
#define ROW_STRIDE 300     // 3 * D_FEAT concatenated output blocks

// ---------------------------------------------------------------------------
// bf16 packing (RNE)
// ---------------------------------------------------------------------------
__device__ __forceinline__ unsigned pack_bf16x2(float a, float b) {
    unsigned ua = __float_as_uint(a);
    unsigned ub = __float_as_uint(b);
    ua += 0x7fffu + ((ua >> 16) & 1u);
    ub += 0x7fffu + ((ub >> 16) & 1u);
    return (ua >> 16) | (ub & 0xffff0000u);
}
__device__ __forceinline__ unsigned long long pack_bf16x4(float a, float b,
                                                          float c, float d) {
    return (unsigned long long)pack_bf16x2(a, b) |
           ((unsigned long long)pack_bf16x2(c, d) << 32);
}

// gather 4 feature elements of `col` (bf16x4 packed table or f32 stride-300)
template <bool BF16>
__device__ __forceinline__ void gather4(const void* __restrict__ prev, int col,
                                        int l, bool act,
                                        float& x0, float& x1, float& x2, float& x3) {
    x0 = x1 = x2 = x3 = 0.f;
    if (!act) return;
    if (BF16) {
        unsigned long long u =
            ((const unsigned long long*)prev)[(size_t)col * QUARTER + l];
        unsigned lo = (unsigned)u, hi = (unsigned)(u >> 32);
        x0 = __uint_as_float(lo << 16);
        x1 = __uint_as_float(lo & 0xffff0000u);
        x2 = __uint_as_float(hi << 16);
        x3 = __uint_as_float(hi & 0xffff0000u);
    } else {
        float4 v = ((const float4*)((const float*)prev + (size_t)col * ROW_STRIDE))[l];
        x0 = v.x; x1 = v.y; x2 = v.z; x3 = v.w;
    }
}

// butterfly sum within each 32-lane half (offsets < 32 never cross halves)
__device__ __forceinline__ float half_reduce(float v) {
    #pragma unroll
    for (int off = 16; off; off >>= 1) v += __shfl_xor(v, off, 64);
    return v;
}

// ---------------------------------------------------------------------------
// Kernel 1: 2 nodes per wave (one per half).
//   out[n,0:100] = tanh(features[n,:]);  ftab0[n] = bf16x4 row (optional)
//   escore0[n] = exp(-dot(l2norm(row), l2norm(none_rel)))  [score in [-1,1]]
// ---------------------------------------------------------------------------
__global__ __launch_bounds__(256) void tanh_score_kernel(
    const float* __restrict__ features,
    float* __restrict__ out,
    unsigned long long* __restrict__ ftab0,
    float* __restrict__ escore0,
    const float* __restrict__ none_rel,
    int N)
{
    int waveId = (int)((blockIdx.x * blockDim.x + threadIdx.x) >> 6);
    int lane = threadIdx.x & 63;
    int half = lane >> 5;
    int l    = lane & 31;
    int n    = waveId * 2 + half;
    const bool valid_n = (n < N);
    const bool act = valid_n && (l < QUARTER);

    float x0 = 0.f, x1 = 0.f, x2 = 0.f, x3 = 0.f;
    if (act) {
        float4 f = ((const float4*)(features + (size_t)n * D_FEAT))[l];
        x0 = tanhf(f.x); x1 = tanhf(f.y); x2 = tanhf(f.z); x3 = tanhf(f.w);
        ((float4*)(out + (size_t)n * ROW_STRIDE))[l] = make_float4(x0, x1, x2, x3);
        if (ftab0) ftab0[(size_t)n * QUARTER + l] = pack_bf16x4(x0, x1, x2, x3);
    }

    float nx = 0.f, ny = 0.f, nz = 0.f, nw = 0.f;
    if (l < QUARTER) {
        float4 v = ((const float4*)none_rel)[l];
        nx = v.x; ny = v.y; nz = v.z; nw = v.w;
    }
    float ss = half_reduce(nx * nx + ny * ny + nz * nz + nw * nw);
    float inv_nr = 1.f / fmaxf(sqrtf(ss), 1e-12f);

    float dot = half_reduce(x0 * nx + x1 * ny + x2 * nz + x3 * nw) * inv_nr;
    float sq  = half_reduce(x0 * x0 + x1 * x1 + x2 * x2 + x3 * x3);
    if (l == 0 && valid_n)
        escore0[n] = expf(-dot / fmaxf(sqrtf(sq), 1e-12f));
}

// ---------------------------------------------------------------------------
// Kernel 2: CSR row offsets via binary search (rows are sorted).
// ---------------------------------------------------------------------------
__global__ void csr_kernel(const int* __restrict__ adj, int E,
                           int* __restrict__ start, int N) {
    int n = blockIdx.x * blockDim.x + threadIdx.x;
    if (n > N) return;
    if (n == N) { start[N] = E; return; }
    int lo = 0, hi = E;
    while (lo < hi) {
        int mid = (lo + hi) >> 1;
        if (adj[2 * mid] < n) lo = mid + 1; else hi = mid;
    }
    start[n] = lo;
}

// ---------------------------------------------------------------------------
// Kernel 3: fused attention layer, 2 nodes per wave.
//  Pass 1: lanes-over-edges per half; (col,w) kept in regs (deg<=32 path);
//          half-butterfly -> denom.  exp needs no max-shift: score in [-1,1].
//  Pass 2: broadcast (col,w) from own half via shfl; one 8B bf16x4 gather
//          per lane per edge; 4-way unroll -> 8 gathers in flight per wave.
//  Epilogue: tanh -> f32 out (+ bf16 table, + next exp-score).
// ---------------------------------------------------------------------------
template <bool BF16>
__global__ __launch_bounds__(256) void attn_kernel(
    const void* __restrict__ prev,
    float* __restrict__ outp,
    unsigned long long* __restrict__ ftab_out,
    const int2* __restrict__ adj2,
    const int* __restrict__ start,
    const float* __restrict__ escore_in,
    float* __restrict__ escore_out,
    const float* __restrict__ none_rel,
    int N)
{
    int waveId = (int)((blockIdx.x * blockDim.x + threadIdx.x) >> 6);
    int lane = threadIdx.x & 63;
    int half = lane >> 5;
    int l    = lane & 31;
    int n    = waveId * 2 + half;
    const bool valid_n = (n < N);
    const bool act = valid_n && (l < QUARTER);
    const int base = half << 5;

    int e0 = 0, e1 = 0;
    if (valid_n) { e0 = start[n]; e1 = start[n + 1]; }
    const int deg = e1 - e0;

    // ---- Pass 1: (col, w) into lane regs; denominator ----
    int   col_reg = 0;
    float w_reg = 0.f, d_l = 0.f;
    if (l < deg) {
        col_reg = adj2[e0 + l].y;
        w_reg   = escore_in[col_reg];
        d_l     = w_reg;
    }
    for (int e = e0 + l + 32; e < e1; e += 32)       // deg > 32 remainder
        d_l += escore_in[adj2[e].y];
    d_l = half_reduce(d_l);
    const float inv_d = (deg > 0) ? 1.f / d_l : 0.f;

    // ---- Pass 2: weighted aggregation ----
    float a0 = 0.f, a1 = 0.f, a2 = 0.f, a3 = 0.f;
    const int nreg = (deg < 32) ? deg : 32;
    int i = 0;
    for (; i + 4 <= nreg; i += 4) {
        int   c0 = __shfl(col_reg, base + i,     64);
        int   c1 = __shfl(col_reg, base + i + 1, 64);
        int   c2 = __shfl(col_reg, base + i + 2, 64);
        int   c3 = __shfl(col_reg, base + i + 3, 64);
        float w0 = __shfl(w_reg,   base + i,     64);
        float w1 = __shfl(w_reg,   base + i + 1, 64);
        float w2 = __shfl(w_reg,   base + i + 2, 64);
        float w3 = __shfl(w_reg,   base + i + 3, 64);
        float p0, p1, p2, p3, q0, q1, q2, q3, r0, r1, r2, r3, s0, s1, s2, s3;
        gather4<BF16>(prev, c0, l, act, p0, p1, p2, p3);
        gather4<BF16>(prev, c1, l, act, q0, q1, q2, q3);
        gather4<BF16>(prev, c2, l, act, r0, r1, r2, r3);
        gather4<BF16>(prev, c3, l, act, s0, s1, s2, s3);
        a0 += w0 * p0; a1 += w0 * p1; a2 += w0 * p2; a3 += w0 * p3;
        a0 += w1 * q0; a1 += w1 * q1; a2 += w1 * q2; a3 += w1 * q3;
        a0 += w2 * r0; a1 += w2 * r1; a2 += w2 * r2; a3 += w2 * r3;
        a0 += w3 * s0; a1 += w3 * s1; a2 += w3 * s2; a3 += w3 * s3;
    }
    for (; i < nreg; ++i) {
        int   c = __shfl(col_reg, base + i, 64);
        float w = __shfl(w_reg,   base + i, 64);
        float p0, p1, p2, p3;
        gather4<BF16>(prev, c, l, act, p0, p1, p2, p3);
        a0 += w * p0; a1 += w * p1; a2 += w * p2; a3 += w * p3;
    }
    for (int e = e0 + 32; e < e1; ++e) {             // deg > 32 remainder (rare)
        int   c = adj2[e].y;                          // uniform within half
        float w = escore_in[c];
        float p0, p1, p2, p3;
        gather4<BF16>(prev, c, l, act, p0, p1, p2, p3);
        a0 += w * p0; a1 += w * p1; a2 += w * p2; a3 += w * p3;
    }

    float r0 = tanhf(a0 * inv_d);
    float r1 = tanhf(a1 * inv_d);
    float r2 = tanhf(a2 * inv_d);
    float r3 = tanhf(a3 * inv_d);
    if (act) {
        ((float4*)(outp + (size_t)n * ROW_STRIDE))[l] = make_float4(r0, r1, r2, r3);
        if (ftab_out) ftab_out[(size_t)n * QUARTER + l] = pack_bf16x4(r0, r1, r2, r3);
    } else {
        r0 = r1 = r2 = r3 = 0.f;
    }

    // ---- Epilogue: next layer's exp-score ----
    if (escore_out) {
        float nx = 0.f, ny = 0.f, nz = 0.f, nw = 0.f;
        if (l < QUARTER) {
            float4 v = ((const float4*)none_rel)[l];
            nx = v.x; ny = v.y; nz = v.z; nw = v.w;
        }
        float ss = half_reduce(nx * nx + ny * ny + nz * nz + nw * nw);
        float inv_nr = 1.f / fmaxf(sqrtf(ss), 1e-12f);
        float dot = half_reduce(r0 * nx + r1 * ny + r2 * nz + r3 * nw) * inv_nr;
        float sq  = half_reduce(r0 * r0 + r1 * r1 + r2 * r2 + r3 * r3);
        if (l == 0 && valid_n)
            escore_out[n] = expf(-dot / fmaxf(sqrtf(sq), 1e-12f));
    }
}

// ---------------------------------------------------------------------------
extern "C" void kernel_launch(void* const* d_in, const int* in_sizes, int n_in,
                              void* d_out, int out_size, void* d_ws, size_t ws_size,
                              hipStream_t stream) {
    const float* features = (const float*)d_in[0];
    // d_in[1] = rel_emb: unused by the reference
    const int*   adj      = (const int*)d_in[2];
    const float* none_rel = (const float*)d_in[3];
    float* out = (float*)d_out;

    const int N = in_sizes[0] / D_FEAT;   // 50000
    const int E = in_sizes[2] / 2;        // 800000

    // ws layout (16B-aligned): start[N+1] | escore0[N] | escore1[N]
    //                          | ftab0[N*25 u64] | ftab1[N*25 u64]
    size_t off = 0;
    auto take = [&](size_t bytes) { size_t o = off; off = (off + bytes + 15) & ~(size_t)15; return o; };
    char* w = (char*)d_ws;
    int*   start   = (int*)  (w + take(sizeof(int)   * (size_t)(N + 1)));
    float* escore0 = (float*)(w + take(sizeof(float) * (size_t)N));
    float* escore1 = (float*)(w + take(sizeof(float) * (size_t)N));
    size_t ftab_off0 = take(sizeof(unsigned long long) * (size_t)N * QUARTER);
    size_t ftab_off1 = take(sizeof(unsigned long long) * (size_t)N * QUARTER);
    const bool use_bf16 = (ws_size >= off);
    unsigned long long* ftab0 = use_bf16 ? (unsigned long long*)(w + ftab_off0) : nullptr;
    unsigned long long* ftab1 = use_bf16 ? (unsigned long long*)(w + ftab_off1) : nullptr;

    const int pairs = (N + 1) / 2;                       // 2 nodes per wave
    const int node_blocks = (pairs * 64 + 255) / 256;
    const int2* adj2 = (const int2*)adj;

    tanh_score_kernel<<<node_blocks, 256, 0, stream>>>(features, out, ftab0,
                                                       escore0, none_rel, N);
    {
        int blocks = (N + 1 + 255) / 256;
        csr_kernel<<<blocks, 256, 0, stream>>>(adj, E, start, N);
    }
    if (use_bf16) {
        attn_kernel<true><<<node_blocks, 256, 0, stream>>>(
            ftab0, out + D_FEAT, ftab1, adj2, start, escore0, escore1, none_rel, N);
        attn_kernel<true><<<node_blocks, 256, 0, stream>>>(
            ftab1, out + 2 * D_FEAT, nullptr, adj2, start, escore1, nullptr, none_rel, N);
    } else {
        attn_kernel<false><<<node_blocks, 256, 0, stream>>>(
            out, out + D_FEAT, nullptr, adj2, start, escore0, escore1, none_rel, N);
        attn_kernel<false><<<node_blocks, 256, 0, stream>>>(
            out + D_FEAT, out + 2 * D_FEAT, nullptr, adj2, start, escore1, nullptr, none_rel, N);
    }
}